// Round 8
// baseline (264.366 us; speedup 1.0000x reference)
//
#include <hip/hip_runtime.h>
#include <math.h>

#define BB 4
#define CC 64
#define DI 128
#define NS 16
#define LL 9216
#define NT (LL / 64)

// scan decomposition
#define GCH 576
#define LCH 16
#define NSEQ 8192      // B*DI*NS
#define SD  512        // B*DI
#define NG 24
#define GS 24          // NG*GS == GCH

typedef __attribute__((ext_vector_type(8))) short bf16x8;
typedef __attribute__((ext_vector_type(4))) float fx4;
#define MFMA16 __builtin_amdgcn_mfma_f32_16x16x32_bf16

static __device__ __forceinline__ unsigned short f2b(float f) {
  unsigned u = __float_as_uint(f);
  u += 0x7fffu + ((u >> 16) & 1u);
  return (unsigned short)(u >> 16);
}
static __device__ __forceinline__ float b2f(unsigned short s) {
  return __uint_as_float(((unsigned)s) << 16);
}
static __device__ __forceinline__ float silu_f(float x) {
  return x / (1.f + __expf(-x));
}
static __device__ __forceinline__ float softplus_f(float v) {
  return fmaxf(v, 0.f) + __logf(1.f + __expf(-fabsf(v)));
}

// ---------------- weight bf16 conversion (once) ----------------
__global__ __launch_bounds__(256) void k_cvt(const float* __restrict__ inw1, const float* __restrict__ xpw1,
                                             const float* __restrict__ ow1, const float* __restrict__ pw1,
                                             const float* __restrict__ inw2, const float* __restrict__ xpw2,
                                             const float* __restrict__ ow2, const float* __restrict__ pw2,
                                             unsigned short* __restrict__ wb) {
  int idx = blockIdx.x * 256 + threadIdx.x;   // < 69632
  int layer = idx >= 34816;
  int e = idx - layer * 34816;
  const float* inw = layer ? inw2 : inw1;
  const float* xpw = layer ? xpw2 : xpw1;
  const float* ow = layer ? ow2 : ow1;
  const float* pw = layer ? pw2 : pw1;
  float v;
  if (e < 16384) v = inw[e];
  else if (e < 22528) { int t = e - 16384; int r = t >> 7, c = t & 127; v = (r < 36) ? xpw[r * 128 + c] : 0.f; }
  else if (e < 30720) v = ow[e - 22528];
  else v = pw[e - 30720];
  wb[idx] = f2b(v);
}

// ---------------- instance-norm moments per (b,c) ----------------
__global__ __launch_bounds__(256) void k_stats(const float* __restrict__ p,
                                               float* __restrict__ stats) {
  int bc = blockIdx.x;
  const float* row = p + (size_t)bc * LL;
  float s = 0.f, s2 = 0.f;
  for (int i = threadIdx.x; i < LL; i += 256) {
    float v = row[i];
    s += v; s2 += v * v;
  }
  #pragma unroll
  for (int o = 32; o > 0; o >>= 1) {
    s += __shfl_down(s, o);
    s2 += __shfl_down(s2, o);
  }
  __shared__ float red[8];
  int w = threadIdx.x >> 6;
  if ((threadIdx.x & 63) == 0) { red[w] = s; red[4 + w] = s2; }
  __syncthreads();
  if (threadIdx.x == 0) {
    float S = red[0] + red[1] + red[2] + red[3];
    float S2 = red[4] + red[5] + red[6] + red[7];
    float m = S * (1.f / LL);
    float var = S2 * (1.f / LL) - m * m;
    stats[bc * 2] = m;
    stats[bc * 2 + 1] = rsqrtf(var + 1e-5f);
  }
}

// ---- fused: transpose + IN + relu + LN + in-proj MFMA -> xf, xin_b, sz_b=silu(z) ----
__global__ __launch_bounds__(256) void k_fusein(const float* __restrict__ p,
                                                const float* __restrict__ stats,
                                                const float* __restrict__ g,
                                                const float* __restrict__ be,
                                                const unsigned short* __restrict__ w_b,
                                                float* __restrict__ xf,
                                                unsigned short* __restrict__ xin_b,
                                                unsigned short* __restrict__ sz_b) {
  int b = blockIdx.x / NT;
  int l0 = (blockIdx.x % NT) * 64;
  __shared__ float T[64][65];
  __shared__ unsigned short Tb[64][72];
  int li = threadIdx.x & 63;
  int c0 = threadIdx.x >> 6;
  #pragma unroll
  for (int j = 0; j < 16; ++j) {
    int c = c0 * 16 + j;
    float m = stats[(b * CC + c) * 2];
    float rs = stats[(b * CC + c) * 2 + 1];
    float v = p[((size_t)(b * CC + c)) * LL + l0 + li];
    T[li][c] = fmaxf((v - m) * rs, 0.f);
  }
  __syncthreads();
  int lane = threadIdx.x & 63;
  int w = threadIdx.x >> 6;
  float gv = g[lane], bv = be[lane];
  for (int j = 0; j < 16; ++j) {
    int row = w * 16 + j;
    float v = T[row][lane];
    float s = v, s2 = v * v;
    #pragma unroll
    for (int o = 32; o > 0; o >>= 1) { s += __shfl_xor(s, o); s2 += __shfl_xor(s2, o); }
    float m = s * (1.f / 64.f);
    float var = s2 * (1.f / 64.f) - m * m;
    float rs = rsqrtf(var + 1e-5f);
    size_t off = ((size_t)b * LL + l0 + row) * CC + lane;
    xf[off] = v;
    Tb[row][lane] = f2b((v - m) * rs * gv + bv);
  }
  __syncthreads();
  int wv = threadIdx.x >> 6;
  int lr = lane & 15, kg = lane >> 4;
  int m0 = wv * 16;
  int rowg0 = blockIdx.x * 64 + m0;
  bf16x8 a0 = *(const bf16x8*)&Tb[m0 + lr][kg * 8];
  bf16x8 a1 = *(const bf16x8*)&Tb[m0 + lr][32 + kg * 8];
  #pragma unroll
  for (int nt = 0; nt < 16; ++nt) {
    bf16x8 b0 = *(const bf16x8*)&w_b[(size_t)(nt * 16 + lr) * CC + kg * 8];
    bf16x8 b1 = *(const bf16x8*)&w_b[(size_t)(nt * 16 + lr) * CC + 32 + kg * 8];
    fx4 c = {0.f, 0.f, 0.f, 0.f};
    c = MFMA16(a0, b0, c, 0, 0, 0);
    c = MFMA16(a1, b1, c, 0, 0, 0);
    #pragma unroll
    for (int r = 0; r < 4; ++r) {
      int row = rowg0 + kg * 4 + r, col = nt * 16 + lr;
      if (col < 128) xin_b[(size_t)row * DI + col] = f2b(c[r]);
      else           sz_b[(size_t)row * DI + col - 128] = f2b(silu_f(c[r]));
    }
  }
}

// ---- depthwise causal conv (K=4) + SiLU -> xc_b bf16 (8 d's per thread) ----
__global__ __launch_bounds__(256) void k_conv(const unsigned short* __restrict__ xin_b,
                                              const float* __restrict__ cw,
                                              const float* __restrict__ cb,
                                              unsigned short* __restrict__ xc_b) {
  int idx = blockIdx.x * 256 + threadIdx.x;   // < BB*LL*16
  int d8 = idx & 15;
  int row = idx >> 4;
  int l = row % LL;
  int cbase = d8 * 8;
  const bf16x8 zv8 = {0, 0, 0, 0, 0, 0, 0, 0};
  bf16x8 x3 = *(const bf16x8*)&xin_b[(size_t)row * DI + cbase];
  bf16x8 x2 = (l >= 1) ? *(const bf16x8*)&xin_b[(size_t)(row - 1) * DI + cbase] : zv8;
  bf16x8 x1 = (l >= 2) ? *(const bf16x8*)&xin_b[(size_t)(row - 2) * DI + cbase] : zv8;
  bf16x8 x0 = (l >= 3) ? *(const bf16x8*)&xin_b[(size_t)(row - 3) * DI + cbase] : zv8;
  bf16x8 out;
  #pragma unroll
  for (int e = 0; e < 8; ++e) {
    int d = cbase + e;
    float4 w4 = *(const float4*)&cw[d * 4];
    float v = cb[d] + b2f((unsigned short)x0[e]) * w4.x + b2f((unsigned short)x1[e]) * w4.y
            + b2f((unsigned short)x2[e]) * w4.z + b2f((unsigned short)x3[e]) * w4.w;
    out[e] = (short)f2b(silu_f(v));
  }
  *(bf16x8*)&xc_b[(size_t)row * DI + cbase] = out;
}

// ---- shared x-proj tile: dblS[16][40] from xc_b (wave0: nt0,1 ; wave1: nt2) ----
static __device__ __forceinline__ void xp_tile(const unsigned short* __restrict__ xc_b,
                                               const unsigned short* __restrict__ xpw_b,
                                               int b, int g, int wv, int lr, int kg,
                                               float (*dblS)[40]) {
  size_t row = (size_t)b * LL + g * LCH + lr;
  fx4 acc0 = {0.f, 0.f, 0.f, 0.f}, acc1 = {0.f, 0.f, 0.f, 0.f};
  int nt0 = wv * 2;
  #pragma unroll
  for (int ks = 0; ks < 4; ++ks) {
    int cbase = ks * 32 + kg * 8;
    bf16x8 a = *(const bf16x8*)&xc_b[row * DI + cbase];
    bf16x8 b0 = *(const bf16x8*)&xpw_b[(size_t)(nt0 * 16 + lr) * DI + cbase];
    acc0 = MFMA16(a, b0, acc0, 0, 0, 0);
    if (wv == 0) {
      bf16x8 b1 = *(const bf16x8*)&xpw_b[(size_t)(16 + lr) * DI + cbase];
      acc1 = MFMA16(a, b1, acc1, 0, 0, 0);
    }
  }
  #pragma unroll
  for (int r = 0; r < 4; ++r) {
    int col0 = nt0 * 16 + lr;
    if (col0 < 36) dblS[kg * 4 + r][col0] = acc0[r];
    if (wv == 0) dblS[kg * 4 + r][16 + lr] = acc1[r];
  }
}

// ---- e1-power a[16] (A_log = log(1..16) broadcast fast path) ----
static __device__ __forceinline__ void a_powers(float dtv, float A0, bool afast,
                                                const float* __restrict__ Alog, int d,
                                                float* a) {
  if (afast) {
    float e1 = __expf(dtv * A0);
    float p2 = e1 * e1, p4 = p2 * p2, p8 = p4 * p4;
    a[0] = e1;      a[1] = p2;      a[2] = p2 * e1;      a[3] = p4;
    a[4] = p4 * e1; a[5] = p4 * p2; a[6] = p4 * p2 * e1; a[7] = p8;
    a[8] = p8 * e1; a[9] = p8 * p2; a[10] = p8 * p2 * e1; a[11] = p8 * p4;
    a[12] = p8 * p4 * e1; a[13] = p8 * p4 * p2; a[14] = p8 * p4 * p2 * e1; a[15] = p8 * p8;
  } else {
    #pragma unroll
    for (int n = 0; n < 16; ++n) a[n] = __expf(dtv * -__expf(Alog[d * NS + n]));
  }
}

// ---- scanAX: x-proj tile (MFMA) + local scan; writes dts, hl ----
__global__ __launch_bounds__(128) void k_scanAX(const unsigned short* __restrict__ xc_b,
                                                const unsigned short* __restrict__ xpw_b,
                                                const float* __restrict__ Alog,
                                                const float* __restrict__ dtw,
                                                const float* __restrict__ dtbp,
                                                float* __restrict__ dts,
                                                float* __restrict__ hl) {
  int g = blockIdx.x % GCH;
  int b = blockIdx.x / GCH;
  __shared__ float dblS[16][40];
  int wv = threadIdx.x >> 6, lane = threadIdx.x & 63;
  int lr = lane & 15, kg = lane >> 4;
  xp_tile(xc_b, xpw_b, b, g, wv, lr, kg, dblS);
  int d = threadIdx.x;
  float A0 = -__expf(Alog[d * NS]);
  bool afast = true;
  #pragma unroll
  for (int n = 1; n < 16; ++n) {
    float An = -__expf(Alog[d * NS + n]);
    afast = afast && (fabsf(An - A0 * (float)(n + 1)) <= 1e-3f * (float)(n + 1) * fabsf(A0));
  }
  float4 w4 = *(const float4*)&dtw[d * 4];
  float dtbv = dtbp[d];
  __syncthreads();
  const unsigned short* xcp = xc_b + ((size_t)b * LL + g * LCH) * DI + d;
  float h[16];
  #pragma unroll
  for (int n = 0; n < 16; ++n) h[n] = 0.f;
  float dtsum = 0.f;
  #pragma unroll 4
  for (int l = 0; l < LCH; ++l) {
    float xcv = b2f(xcp[(size_t)l * DI]);
    float4 q = *(float4*)&dblS[l][0];
    float v = dtbv + q.x * w4.x + q.y * w4.y + q.z * w4.z + q.w * w4.w;
    float dtv = softplus_f(v);
    float dx = dtv * xcv;
    dtsum += dtv;
    float4 b0 = *(float4*)&dblS[l][4];
    float4 b1 = *(float4*)&dblS[l][8];
    float4 b2 = *(float4*)&dblS[l][12];
    float4 b3 = *(float4*)&dblS[l][16];
    float a[16];
    a_powers(dtv, A0, afast, Alog, d, a);
    h[0]  = a[0]  * h[0]  + dx * b0.x;  h[1]  = a[1]  * h[1]  + dx * b0.y;
    h[2]  = a[2]  * h[2]  + dx * b0.z;  h[3]  = a[3]  * h[3]  + dx * b0.w;
    h[4]  = a[4]  * h[4]  + dx * b1.x;  h[5]  = a[5]  * h[5]  + dx * b1.y;
    h[6]  = a[6]  * h[6]  + dx * b1.z;  h[7]  = a[7]  * h[7]  + dx * b1.w;
    h[8]  = a[8]  * h[8]  + dx * b2.x;  h[9]  = a[9]  * h[9]  + dx * b2.y;
    h[10] = a[10] * h[10] + dx * b2.z;  h[11] = a[11] * h[11] + dx * b2.w;
    h[12] = a[12] * h[12] + dx * b3.x;  h[13] = a[13] * h[13] + dx * b3.y;
    h[14] = a[14] * h[14] + dx * b3.z;  h[15] = a[15] * h[15] + dx * b3.w;
  }
  dts[(size_t)g * SD + b * DI + d] = dtsum;
  size_t o = (size_t)g * NSEQ + ((size_t)b * DI + d) * NS;
  #pragma unroll
  for (int j = 0; j < 4; ++j)
    *(float4*)&hl[o + j * 4] = make_float4(h[j * 4], h[j * 4 + 1], h[j * 4 + 2], h[j * 4 + 3]);
}

// ---- scan2a: per-group aggregates (a recomputed from dtsum — exact) ----
__global__ __launch_bounds__(256) void k_scan2a(const float* __restrict__ dts,
                                                const float* __restrict__ hl,
                                                const float* __restrict__ Alog,
                                                float* __restrict__ gap,
                                                float* __restrict__ ghl) {
  int t = blockIdx.x * 256 + threadIdx.x;   // < NG*NSEQ
  int grp = t >> 13, seq = t & (NSEQ - 1);
  int sd = seq >> 4;
  float An = -__expf(Alog[seq & (DI * NS - 1)]);
  float A = 1.f, H = 0.f;
  int c0 = grp * GS;
  #pragma unroll 4
  for (int c = 0; c < GS; ++c) {
    float a = __expf(An * dts[(size_t)(c0 + c) * SD + sd]);
    H = a * H + hl[(size_t)(c0 + c) * NSEQ + seq];
    A *= a;
  }
  gap[t] = A;
  ghl[t] = H;
}

// ---- scan2bc: redundant group-prefix + chunk carries ----
__global__ __launch_bounds__(256) void k_scan2bc(const float* __restrict__ dts,
                                                 const float* __restrict__ hl,
                                                 const float* __restrict__ gap,
                                                 const float* __restrict__ ghl,
                                                 const float* __restrict__ Alog,
                                                 float* __restrict__ hi) {
  int t = blockIdx.x * 256 + threadIdx.x;   // < NG*NSEQ
  int grp = t >> 13, seq = t & (NSEQ - 1);
  int sd = seq >> 4;
  float An = -__expf(Alog[seq & (DI * NS - 1)]);
  float h = 0.f;
  for (int gg = 0; gg < grp; ++gg)
    h = gap[gg * NSEQ + seq] * h + ghl[gg * NSEQ + seq];
  int c0 = grp * GS;
  #pragma unroll 4
  for (int c = 0; c < GS; ++c) {
    float a = __expf(An * dts[(size_t)(c0 + c) * SD + sd]);
    hi[(size_t)(c0 + c) * NSEQ + seq] = h;
    h = a * h + hl[(size_t)(c0 + c) * NSEQ + seq];
  }
}

// ---- scanCO: x-proj tile + replay + out-proj + pr-proj (full-K, split-N waves) ----
__global__ __launch_bounds__(128) void k_scanCO(const unsigned short* __restrict__ xc_b,
                                                const unsigned short* __restrict__ xpw_b,
                                                const unsigned short* __restrict__ sz_b,
                                                const float* __restrict__ Alog,
                                                const float* __restrict__ dtw,
                                                const float* __restrict__ dtbp,
                                                const float* __restrict__ Dp,
                                                const float* __restrict__ hi,
                                                const unsigned short* __restrict__ ow_b,
                                                const float* __restrict__ xf,
                                                const float* __restrict__ skipv,
                                                const unsigned short* __restrict__ pw_b,
                                                const float* __restrict__ pb,
                                                const float* __restrict__ ident,
                                                float* __restrict__ dst, int addid) {
  int g = blockIdx.x % GCH;
  int b = blockIdx.x / GCH;
  __shared__ float dblS[16][40];
  __shared__ unsigned short yS[16][136];
  __shared__ unsigned short tmpS[16][72];
  int wv = threadIdx.x >> 6, lane = threadIdx.x & 63;
  int lr = lane & 15, kg = lane >> 4;
  xp_tile(xc_b, xpw_b, b, g, wv, lr, kg, dblS);
  int d = threadIdx.x;
  float A0 = -__expf(Alog[d * NS]);
  bool afast = true;
  #pragma unroll
  for (int n = 1; n < 16; ++n) {
    float An = -__expf(Alog[d * NS + n]);
    afast = afast && (fabsf(An - A0 * (float)(n + 1)) <= 1e-3f * (float)(n + 1) * fabsf(A0));
  }
  float4 w4 = *(const float4*)&dtw[d * 4];
  float dtbv = dtbp[d];
  float Dv = Dp[d];
  __syncthreads();
  size_t o = (size_t)g * NSEQ + ((size_t)b * DI + d) * NS;
  float h[16];
  #pragma unroll
  for (int j = 0; j < 4; ++j) {
    float4 hv = *(const float4*)&hi[o + j * 4];
    h[j * 4 + 0] = hv.x; h[j * 4 + 1] = hv.y; h[j * 4 + 2] = hv.z; h[j * 4 + 3] = hv.w;
  }
  size_t base = ((size_t)b * LL + g * LCH) * DI + d;
  #pragma unroll 4
  for (int l = 0; l < LCH; ++l) {
    float xcv = b2f(xc_b[base + (size_t)l * DI]);
    float sg = b2f(sz_b[base + (size_t)l * DI]);
    float4 q = *(float4*)&dblS[l][0];
    float v = dtbv + q.x * w4.x + q.y * w4.y + q.z * w4.z + q.w * w4.w;
    float dtv = softplus_f(v);
    float4 b0 = *(float4*)&dblS[l][4];
    float4 b1 = *(float4*)&dblS[l][8];
    float4 b2 = *(float4*)&dblS[l][12];
    float4 b3 = *(float4*)&dblS[l][16];
    float4 c0 = *(float4*)&dblS[l][20];
    float4 c1 = *(float4*)&dblS[l][24];
    float4 c2 = *(float4*)&dblS[l][28];
    float4 c3 = *(float4*)&dblS[l][32];
    float a[16];
    a_powers(dtv, A0, afast, Alog, d, a);
    float dx = dtv * xcv;
    float yv = Dv * xcv;
    h[0]  = a[0]  * h[0]  + dx * b0.x;  yv += h[0]  * c0.x;
    h[1]  = a[1]  * h[1]  + dx * b0.y;  yv += h[1]  * c0.y;
    h[2]  = a[2]  * h[2]  + dx * b0.z;  yv += h[2]  * c0.z;
    h[3]  = a[3]  * h[3]  + dx * b0.w;  yv += h[3]  * c0.w;
    h[4]  = a[4]  * h[4]  + dx * b1.x;  yv += h[4]  * c1.x;
    h[5]  = a[5]  * h[5]  + dx * b1.y;  yv += h[5]  * c1.y;
    h[6]  = a[6]  * h[6]  + dx * b1.z;  yv += h[6]  * c1.z;
    h[7]  = a[7]  * h[7]  + dx * b1.w;  yv += h[7]  * c1.w;
    h[8]  = a[8]  * h[8]  + dx * b2.x;  yv += h[8]  * c2.x;
    h[9]  = a[9]  * h[9]  + dx * b2.y;  yv += h[9]  * c2.y;
    h[10] = a[10] * h[10] + dx * b2.z;  yv += h[10] * c2.z;
    h[11] = a[11] * h[11] + dx * b2.w;  yv += h[11] * c2.w;
    h[12] = a[12] * h[12] + dx * b3.x;  yv += h[12] * c3.x;
    h[13] = a[13] * h[13] + dx * b3.y;  yv += h[13] * c3.y;
    h[14] = a[14] * h[14] + dx * b3.z;  yv += h[14] * c3.z;
    h[15] = a[15] * h[15] + dx * b3.w;  yv += h[15] * c3.w;
    yS[l][d] = f2b(yv * sg);
  }
  __syncthreads();
  // phase O: out-proj, full-K, wave wv computes output cols wv*32 .. wv*32+31
  {
    fx4 oacc[2];
    oacc[0] = (fx4){0.f, 0.f, 0.f, 0.f};
    oacc[1] = (fx4){0.f, 0.f, 0.f, 0.f};
    #pragma unroll
    for (int ks = 0; ks < 4; ++ks) {
      int cbase = ks * 32 + kg * 8;
      bf16x8 a = *(const bf16x8*)&yS[lr][cbase];
      #pragma unroll
      for (int j = 0; j < 2; ++j) {
        int nt = wv * 2 + j;
        bf16x8 bfr = *(const bf16x8*)&ow_b[(size_t)(nt * 16 + lr) * DI + cbase];
        oacc[j] = MFMA16(a, bfr, oacc[j], 0, 0, 0);
      }
    }
    float sk = skipv[0];
    #pragma unroll
    for (int j = 0; j < 2; ++j) {
      int nt = wv * 2 + j;
      #pragma unroll
      for (int r = 0; r < 4; ++r) {
        int rowl = kg * 4 + r, col = nt * 16 + lr;
        size_t grow = (size_t)b * LL + g * LCH + rowl;
        tmpS[rowl][col] = f2b(oacc[j][r] + sk * xf[grow * CC + col]);
      }
    }
  }
  __syncthreads();
  // phase P: pr-proj, full-K, wave wv computes output channels wv*32 .. wv*32+31
  {
    fx4 pacc[2];
    pacc[0] = (fx4){0.f, 0.f, 0.f, 0.f};
    pacc[1] = (fx4){0.f, 0.f, 0.f, 0.f};
    #pragma unroll
    for (int ks = 0; ks < 2; ++ks) {
      int cbase = ks * 32 + kg * 8;
      bf16x8 bfrag = *(const bf16x8*)&tmpS[lr][cbase];
      #pragma unroll
      for (int j = 0; j < 2; ++j) {
        int ct = wv * 2 + j;
        bf16x8 a = *(const bf16x8*)&pw_b[(size_t)(ct * 16 + lr) * CC + cbase];
        pacc[j] = MFMA16(a, bfrag, pacc[j], 0, 0, 0);
      }
    }
    #pragma unroll
    for (int j = 0; j < 2; ++j) {
      int ct = wv * 2 + j;
      #pragma unroll
      for (int r = 0; r < 4; ++r) {
        int c = ct * 16 + kg * 4 + r;
        int lpos = g * LCH + lr;
        size_t off = ((size_t)(b * CC + c)) * LL + lpos;
        float val = pacc[j][r] + pb[c];
        if (addid) val += ident[off];
        dst[off] = val;
      }
    }
  }
}

extern "C" void kernel_launch(void* const* d_in, const int* in_sizes, int n_in,
                              void* d_out, int out_size, void* d_ws, size_t ws_size,
                              hipStream_t stream) {
  const float* x = (const float*)d_in[0];
  float* ws = (float*)d_ws;
  float* stats = ws;                                        //      1024 floats
  float* xf    = ws + 1024;                                 //  2359296
  unsigned short* xin_b = (unsigned short*)(ws + 2360320);  //  4718592 shorts
  unsigned short* sz_b  = (unsigned short*)(ws + 4719616);  //  4718592 shorts
  unsigned short* xc_b  = (unsigned short*)(ws + 7078912);  //  4718592 shorts
  float* dts   = ws + 9438208;                              //   294912
  float* hl    = ws + 9733120;                              //  4718592 (dead after scan2bc -> inter)
  float* hi    = ws + 14451712;                             //  4718592
  float* gap   = ws + 19170304;                             //   196608
  float* ghl   = ws + 19366912;                             //   196608
  unsigned short* wb = (unsigned short*)(ws + 19563520);    //    69632 shorts
  float* inter = hl;   // hl dead after k_scan2bc; scanCO(L0) writes it; L1 consumes it
                       // in stats/fusein BEFORE scanAX(L1) rewrites hl.
  float* outp  = (float*)d_out;

  k_cvt<<<272, 256, 0, stream>>>((const float*)d_in[3], (const float*)d_in[6],
                                 (const float*)d_in[11], (const float*)d_in[13],
                                 (const float*)d_in[17], (const float*)d_in[20],
                                 (const float*)d_in[25], (const float*)d_in[27], wb);

  const float* cur = x;
  for (int layer = 0; layer < 2; ++layer) {
    const int p0 = 1 + 14 * layer;
    const float* ln_g   = (const float*)d_in[p0 + 0];
    const float* ln_b   = (const float*)d_in[p0 + 1];
    const float* conv_w = (const float*)d_in[p0 + 3];
    const float* conv_b = (const float*)d_in[p0 + 4];
    const float* dt_w   = (const float*)d_in[p0 + 6];
    const float* dt_b   = (const float*)d_in[p0 + 7];
    const float* A_log  = (const float*)d_in[p0 + 8];
    const float* Dp     = (const float*)d_in[p0 + 9];
    const float* skip   = (const float*)d_in[p0 + 11];
    const float* pr_b   = (const float*)d_in[p0 + 13];
    const unsigned short* inw_b = wb + (size_t)layer * 34816;
    const unsigned short* xpw_b = inw_b + 16384;
    const unsigned short* ow_b  = inw_b + 22528;
    const unsigned short* pw_b  = inw_b + 30720;
    float* dst = (layer == 0) ? inter : outp;

    k_stats  <<<BB * CC, 256, 0, stream>>>(cur, stats);
    k_fusein <<<BB * NT, 256, 0, stream>>>(cur, stats, ln_g, ln_b, inw_b, xf, xin_b, sz_b);
    k_conv   <<<(BB * LL * 16) / 256, 256, 0, stream>>>(xin_b, conv_w, conv_b, xc_b);
    k_scanAX <<<BB * GCH, 128, 0, stream>>>(xc_b, xpw_b, A_log, dt_w, dt_b, dts, hl);
    k_scan2a <<<(NG * NSEQ) / 256, 256, 0, stream>>>(dts, hl, A_log, gap, ghl);
    k_scan2bc<<<(NG * NSEQ) / 256, 256, 0, stream>>>(dts, hl, gap, ghl, A_log, hi);
    k_scanCO <<<BB * GCH, 128, 0, stream>>>(xc_b, xpw_b, sz_b, A_log, dt_w, dt_b, Dp,
                                            hi, ow_b, xf, skip, pw_b, pr_b, x, dst, layer);
    cur = inter;
  }
}